// Round 7
// baseline (398.048 us; speedup 1.0000x reference)
//
#include <hip/hip_runtime.h>
#include <math.h>

// Problem constants
#define NB   16
#define CC   256
#define NPTS 16384       // 16*32*32
#define KK   8192
#define Z_OUT 4194304    // NPTS*CC
// d_out: [0,Z_OUT) z_q_out (BCHW), [Z_OUT,Z_OUT+NPTS) idx as float, [Z_OUT+NPTS] loss
// d_out scratch reuse timeline:
//   before k_cand done: zb16 = bf16[16384][256] at slot 0, ebf = bf16[8192][256] at
//     slot 2,097,152
//   k_final overwrites [0, Z_OUT) with z_q BCHW (zb16/ebf dead by then).

// ws layout (floats)
#define WS_ENORM 16448
#define WS_CCNT  24640                // int[16384] candidate counts
#define WS_CIDX  41024                // int[16384][64] candidate k lists
#define CAND_CAP 64
#define LCAP     96                   // pre-filter per-n LDS list capacity
#define MARGIN   4.0e-4f              // > 2*eps_bf16 + d-quantum + enorm spread

typedef short v8s __attribute__((ext_vector_type(8)));
typedef float v4f __attribute__((ext_vector_type(4)));

__device__ __forceinline__ unsigned short f2bf(float f) {   // RNE, finite inputs
    unsigned int u = __float_as_uint(f);
    return (unsigned short)((u + 0x7FFFu + ((u >> 16) & 1u)) >> 16);
}
// monotone float<->uint encoding for atomicMax on floats of any sign
__device__ __forceinline__ unsigned fenc(float f) {
    unsigned u = __float_as_uint(f);
    return (u & 0x80000000u) ? ~u : (u | 0x80000000u);
}
__device__ __forceinline__ float fdec(unsigned m) {
    unsigned u = (m & 0x80000000u) ? (m & 0x7fffffffu) : ~m;
    return __uint_as_float(u);
}

// ---------------- P0: z BCHW fp32 -> zb16[n][c] bf16 (transpose+cast) ----------------
__global__ void k_prep_z(const float* __restrict__ z, unsigned short* __restrict__ zb16) {
    __shared__ float ts[64][65];
    const int hw0 = blockIdx.x * 64, c0 = blockIdx.y * 64, b = blockIdx.z;
    const int tid = threadIdx.x;
#pragma unroll
    for (int p = 0; p < 4; ++p) {
        int u = p * 256 + tid;
        int ci = u >> 4, j4 = (u & 15) << 2;
        float4 v = *(const float4*)(z + (size_t)b * 262144 + (size_t)(c0 + ci) * 1024 + hw0 + j4);
        ts[ci][j4 + 0] = v.x; ts[ci][j4 + 1] = v.y; ts[ci][j4 + 2] = v.z; ts[ci][j4 + 3] = v.w;
    }
    __syncthreads();
#pragma unroll
    for (int p = 0; p < 4; ++p) {
        int u = p * 256 + tid;
        int hj = u >> 4, i4 = (u & 15) << 2;
        ushort4 o = make_ushort4(f2bf(ts[i4 + 0][hj]), f2bf(ts[i4 + 1][hj]),
                                 f2bf(ts[i4 + 2][hj]), f2bf(ts[i4 + 3][hj]));
        *(ushort4*)(zb16 + (size_t)(b * 1024 + hw0 + hj) * 256 + c0 + i4) = o;
    }
}

// ---------------- P1: emb fp32 -> ebf[k][c] bf16, fused with enorm + lossAcc=0 -------
// 2048 blocks x 256 thr: 4 rows/block, 1 wave/row; lane holds float4 of the row.
__global__ void k_prep_e(const float* __restrict__ emb, unsigned short* __restrict__ ebf,
                         float* __restrict__ enorm, float* __restrict__ lossAcc) {
    const int w = threadIdx.x >> 6, lane = threadIdx.x & 63;
    const int k = blockIdx.x * 4 + w;
    const int i = k * CC + lane * 4;
    float4 v = *(const float4*)(emb + i);
    *(ushort4*)(ebf + i) = make_ushort4(f2bf(v.x), f2bf(v.y), f2bf(v.z), f2bf(v.w));
    float s = v.x * v.x + v.y * v.y + v.z * v.z + v.w * v.w;
    for (int off = 32; off > 0; off >>= 1) s += __shfl_down(s, off);
    if (lane == 0) enorm[k] = s;
    if (blockIdx.x == 0 && threadIdx.x == 0) lossAcc[0] = 0.0f;
}

// ---------------- Phase 1: single-sweep MFMA candidate generation, B-in-registers ----
// 256 blocks x 512 thr (8 waves, 2 waves/SIMD, 256-reg budget). Block = 64 n.
// Wave tiling CHANGED from 64kx64n to 128kx32n: wave w -> n-half nh=w&1, k-wave
// kw=w>>1. The wave's full B operand (its 32 z-rows x 256 c) = 2 nt x 8 cc fragments
// = 64 VGPR, loaded from zb16 ONCE -- NO LDS staging, NO ds_read, NO lgkmcnt in the
// hot loop (round-6 counters: 150 us invariant under schedule changes; two latency
// chains (vmcnt A + lgkmcnt B) with only ~150 cyc MFMA per step to hide them; this
// removes one chain and doubles MFMA per A-byte).
// k coverage: k-wave kw sweeps chunks ci = s*4 + kw (s=0..15), chunk = 128 k,
// strided so all waves/blocks share a sliding ~512 KB ebf window (L2-resident).
// A (e-rows) ping-pong prefetched one cc-step ahead (depth-1, 64 VGPR).
// Reg budget: breg 64 + aP/aN 64 + acc 64 (AGPR) + misc ~30 < 256. Spill tripwire:
// WRITE_SIZE (clean run ~0.6 MB).
// Candidate semantics unchanged: progressive threshold max(shared runmax, own chunk
// max) - MARGIN (superset-safe under staleness), (k,dot) to LDS lists, exact final
// filter vs TRUE block-global max, overflow -> full-scan fallback.
// mfma_f32_16x16x32_bf16: A[m=lane&15][c=(lane>>4)*8+j]; B[c][n=lane&15];
// D: col(n)=lane&15, row(k)=(lane>>4)*4+reg.
__global__ __launch_bounds__(512, 2)
void k_cand(const unsigned short* __restrict__ zb16, const unsigned short* __restrict__ ebf,
            int* __restrict__ candCnt, int* __restrict__ candI) {
    __shared__ unsigned runmaxU[64];        // ordered-uint running max per n
    __shared__ int      cnt[64];
    __shared__ int      lstK[64][LCAP];     // 24 KB
    __shared__ float    lstD[64][LCAP];     // 24 KB

    const int tid  = threadIdx.x;
    const int lane = tid & 63;
    const int w    = tid >> 6;              // 0..7
    const int nb   = blockIdx.x << 6;
    const int m16  = lane & 15, q = lane >> 4;
    const int nh   = w & 1;                 // n-half (32 n each)
    const int kw   = w >> 1;                // k-wave 0..3

    if (tid < 64) { runmaxU[tid] = 0x007FFFFFu; /* fenc(-inf) */ cnt[tid] = 0; }

    // B fully in registers: 2 ntile x 8 cchunk fragments (same per-lane fragment
    // pattern previously staged through LDS -- identical data, now direct).
    v8s breg[2][8];
#pragma unroll
    for (int nt = 0; nt < 2; ++nt)
#pragma unroll
        for (int cc = 0; cc < 8; ++cc)
            breg[nt][cc] = *(const v8s*)(zb16 +
                (size_t)(nb + nh * 32 + nt * 16 + m16) * 256 + cc * 32 + q * 8);

    auto loadA = [&](v8s (&a)[8], int kbr, int cc) {
#pragma unroll
        for (int kt = 0; kt < 8; ++kt)
            a[kt] = *(const v8s*)(ebf + (size_t)(kbr + (kt << 4) + m16) * 256 + (cc << 5) + q * 8);
    };

    v8s aP[8], aN[8];
    loadA(aP, kw << 7, 0);         // first chunk (s=0 -> ci=kw), cc=0
    __syncthreads();               // runmaxU/cnt init visible

#pragma unroll 1
    for (int s = 0; s < 16; ++s) {
        const int kb  = ((s << 2) + kw) << 7;          // chunk base, 128 k
        const int kbn = (s < 15) ? kb + 512 : kb;      // next chunk (ci+4)
        v4f acc[16];
#pragma unroll
        for (int i = 0; i < 16; ++i) acc[i] = (v4f){0.f, 0.f, 0.f, 0.f};

#pragma unroll
        for (int cc = 0; cc < 8; ++cc) {
            if ((cc & 1) == 0) {
                loadA(aN, kb, cc + 1);                 // prefetch next cc
#pragma unroll
                for (int kt = 0; kt < 8; ++kt)
#pragma unroll
                    for (int nt = 0; nt < 2; ++nt)
                        acc[kt * 2 + nt] = __builtin_amdgcn_mfma_f32_16x16x32_bf16(
                            aP[kt], breg[nt][cc], acc[kt * 2 + nt], 0, 0, 0);
            } else {
                if (cc < 7) loadA(aP, kb, cc + 1);
                else        loadA(aP, kbn, 0);         // prefetch next s across epilogue
#pragma unroll
                for (int kt = 0; kt < 8; ++kt)
#pragma unroll
                    for (int nt = 0; nt < 2; ++nt)
                        acc[kt * 2 + nt] = __builtin_amdgcn_mfma_f32_16x16x32_bf16(
                            aN[kt], breg[nt][cc], acc[kt * 2 + nt], 0, 0, 0);
            }
        }

        // chunk epilogue: own-chunk max per n-column, merge into shared runmax, push.
        float mx[2];
#pragma unroll
        for (int nt = 0; nt < 2; ++nt) {
            float m = acc[nt][0];
#pragma unroll
            for (int kt = 0; kt < 8; ++kt)
#pragma unroll
                for (int r = 0; r < 4; ++r) m = fmaxf(m, acc[kt * 2 + nt][r]);
            m = fmaxf(m, __shfl_xor(m, 16));
            m = fmaxf(m, __shfl_xor(m, 32));
            mx[nt] = m;
            if (lane < 16) atomicMax(&runmaxU[nh * 32 + nt * 16 + lane], fenc(m));
        }
#pragma unroll
        for (int nt = 0; nt < 2; ++nt) {
            const int nl = nh * 32 + nt * 16 + m16;
            const float thr = fmaxf(fdec(runmaxU[nl]), mx[nt]) - MARGIN;
#pragma unroll
            for (int kt = 0; kt < 8; ++kt)
#pragma unroll
                for (int r = 0; r < 4; ++r) {
                    if (acc[kt * 2 + nt][r] >= thr) {
                        int k = kb + (kt << 4) + q * 4 + r;
                        int pos = atomicAdd(&cnt[nl], 1);
                        if (pos < LCAP) { lstK[nl][pos] = k; lstD[nl][pos] = acc[kt * 2 + nt][r]; }
                    }
                }
        }
        if (s == 3 || s == 9) __syncthreads();   // bound cross-wave staleness
    }

    __syncthreads();   // all pushes + atomicMax done; runmaxU now TRUE global max per n
    if (tid < 64) {
        const int n = nb + tid;
        const int c = cnt[tid];
        if (c > LCAP) {
            candCnt[n] = KK;               // overflow -> exact full-scan fallback
        } else {
            const float thr = fdec(runmaxU[tid]) - MARGIN;
            int kept = 0;
            for (int i = 0; i < c; ++i) {
                if (lstD[tid][i] >= thr) {
                    if (kept < CAND_CAP) candI[(size_t)n * CAND_CAP + kept] = lstK[tid][i];
                    ++kept;
                }
            }
            candCnt[n] = (kept > CAND_CAP) ? KK : kept;
        }
    }
}

// ---------------- Phase 2 (fused): transpose-stage + rescore + gather + loss ---------
// 256 blocks x 256 thr (4 waves). Block = 64 consecutive n (b = bid>>4, hw0 =
// (bid&15)*64). z tile staged TRANSPOSED in LDS zl[hw][c] (66.6 KB, pad 260 so rows
// are 1040 B = 16B-aligned for b128 reads). Replaces k_tr_z + k_znorm + k_rescore2 +
// k_gather (saves 32 MB HBM round-trip + 3 launches).
// Rescore: wave per n, lane l holds zl[j][4l..4l+3] -- IDENTICAL values and dot chain
// to the round-6 zt path (b128 row read, 4 fmaf, xor-butterfly 1..32). zn is now a
// butterfly instead of the old serial kernel -- it shifts all d of an n equally, so
// argmin/tie-break are invariant. d = (zn + enorm[k]) - (p+p); ties -> smallest k.
__global__ __launch_bounds__(256)
void k_final(const float* __restrict__ z, const float* __restrict__ emb,
             const float* __restrict__ enorm, const int* __restrict__ candCnt,
             const int* __restrict__ candI, float* __restrict__ out,
             float* __restrict__ idxf, float* __restrict__ lossAcc) {
    __shared__ float zl[64][260];     // [hw][c], 66.6 KB
    __shared__ int   kis[64];
    __shared__ float red[256];
    const int bid = blockIdx.x;
    const int b = bid >> 4, hw0 = (bid & 15) << 6;
    const int tid = threadIdx.x;
    const int lane = tid & 63, w = tid >> 6;

    // stage: read float4 along hw (coalesced), scatter-transpose into zl[hw][c]
#pragma unroll
    for (int p = 0; p < 16; ++p) {
        const int u = p * 256 + tid;
        const int c = u >> 4, j4 = (u & 15) << 2;
        float4 v = *(const float4*)(z + (size_t)b * 262144 + (size_t)c * 1024 + hw0 + j4);
        zl[j4 + 0][c] = v.x; zl[j4 + 1][c] = v.y; zl[j4 + 2][c] = v.z; zl[j4 + 3][c] = v.w;
    }
    __syncthreads();

    // rescore: wave per n, 16 n per wave
#pragma unroll 1
    for (int rr = 0; rr < 16; ++rr) {
        const int j = w * 16 + rr;
        const int n = b * 1024 + hw0 + j;
        const float4 zv = *(const float4*)&zl[j][lane * 4];    // conflict-free b128
        float zn = zv.x * zv.x;
        zn = fmaf(zv.y, zv.y, zn); zn = fmaf(zv.z, zv.z, zn); zn = fmaf(zv.w, zv.w, zn);
#pragma unroll
        for (int off = 1; off < 64; off <<= 1) zn += __shfl_xor(zn, off);
        const int cnt = candCnt[n];
        float bd = __builtin_inff();
        int   bk = 0x7fffffff;
        if (cnt <= CAND_CAP) {
#pragma unroll 1
            for (int i = 0; i < cnt; ++i) {
                const int k = candI[(size_t)n * CAND_CAP + i];
                const float4 ev = *(const float4*)(emb + (size_t)k * CC + lane * 4);
                float p = zv.x * ev.x;
                p = fmaf(zv.y, ev.y, p);
                p = fmaf(zv.z, ev.z, p);
                p = fmaf(zv.w, ev.w, p);
#pragma unroll
                for (int off = 1; off < 64; off <<= 1) p += __shfl_xor(p, off);
                const float d = (zn + enorm[k]) - (p + p);
                if (d < bd || (d == bd && k < bk)) { bd = d; bk = k; }
            }
        } else {
            // overflow fallback: exact full scan, ascending k keeps min-k
#pragma unroll 1
            for (int k = 0; k < KK; ++k) {
                const float4 ev = *(const float4*)(emb + (size_t)k * CC + lane * 4);
                float p = zv.x * ev.x;
                p = fmaf(zv.y, ev.y, p);
                p = fmaf(zv.z, ev.z, p);
                p = fmaf(zv.w, ev.w, p);
#pragma unroll
                for (int off = 1; off < 64; off <<= 1) p += __shfl_xor(p, off);
                const float d = (zn + enorm[k]) - (p + p);
                if (d < bd) { bd = d; bk = k; }
            }
        }
        if (lane == 0) { idxf[n] = (float)bk; kis[j] = bk; }
    }
    __syncthreads();

    // gather z_q (BCHW, coalesced along hw) + loss partials from the LDS tile
    const int j  = lane;             // hw within tile
    const int cg = w;                // c-group of 64
    const int ki0 = kis[j];
    const float* ep = emb + (size_t)ki0 * CC;
    float ls = 0.0f;
#pragma unroll 4
    for (int c = cg * 64; c < cg * 64 + 64; ++c) {
        float e  = ep[c];
        float zv = zl[j][c];
        out[(size_t)b * 262144 + (size_t)c * 1024 + hw0 + j] = e;
        float df = e - zv;
        ls = fmaf(df, df, ls);
    }
    red[tid] = ls;
    __syncthreads();
    for (int s2 = 128; s2 > 0; s2 >>= 1) {
        if (tid < s2) red[tid] += red[tid + s2];
        __syncthreads();
    }
    if (tid == 0) atomicAdd(lossAcc, red[0]);
}

// ---------------- finalize loss ----------------
__global__ void k_loss(const float* __restrict__ lossAcc, float* __restrict__ outLoss) {
    if (threadIdx.x == 0) {
        float m = lossAcc[0] * (1.0f / 4194304.0f);
        outLoss[0] = m + 0.25f * m;
    }
}

extern "C" void kernel_launch(void* const* d_in, const int* in_sizes, int n_in,
                              void* d_out, int out_size, void* d_ws, size_t ws_size,
                              hipStream_t stream) {
    const float* z   = (const float*)d_in[0];
    const float* emb = (const float*)d_in[1];
    float* outf = (float*)d_out;
    float* wsf  = (float*)d_ws;

    float* lossAcc = wsf;
    float* enorm   = wsf + WS_ENORM;
    int*   candCnt = (int*)(wsf + WS_CCNT);
    int*   candI   = (int*)(wsf + WS_CIDX);

    // d_out z_q region doubles as scratch: bf16 zb16/ebf until k_cand completes,
    // then k_final overwrites it with z_q.
    unsigned short* zb16 = (unsigned short*)outf;                  // 8 MB
    unsigned short* ebf  = (unsigned short*)(outf + 2097152);      // 4 MB

    k_prep_e<<<2048, 256, 0, stream>>>(emb, ebf, enorm, lossAcc);
    k_prep_z<<<dim3(16, 4, 16), 256, 0, stream>>>(z, zb16);
    k_cand<<<256, 512, 0, stream>>>(zb16, ebf, candCnt, candI);
    k_final<<<256, 256, 0, stream>>>(z, emb, enorm, candCnt, candI,
                                     outf, outf + Z_OUT, lossAcc);
    k_loss<<<1, 64, 0, stream>>>(lossAcc, outf + Z_OUT + NPTS);
}

// Round 8
// 257.920 us; speedup vs baseline: 1.5433x; 1.5433x over previous
//
#include <hip/hip_runtime.h>
#include <math.h>

// Problem constants
#define NB   16
#define CC   256
#define NPTS 16384       // 16*32*32
#define KK   8192
#define Z_OUT 4194304    // NPTS*CC
// d_out: [0,Z_OUT) z_q_out (BCHW), [Z_OUT,Z_OUT+NPTS) idx as float, [Z_OUT+NPTS] loss
// d_out scratch reuse timeline:
//   before k_cand done: zb16 = bf16[16384][256] at slot 0, ebf = bf16[8192][256] at
//     slot 2,097,152
//   k_final overwrites [0, Z_OUT) with z_q BCHW (zb16/ebf dead by then).

// ws layout (floats)
#define WS_ENORM 16448
#define WS_CCNT  24640                // int[16384] candidate counts
#define WS_CIDX  41024                // int[16384][64] candidate k lists
#define CAND_CAP 64
#define LCAP     96                   // pre-filter per-n LDS list capacity
#define MARGIN   4.0e-4f              // > 2*eps_bf16 + d-quantum + enorm spread

typedef short v8s __attribute__((ext_vector_type(8)));
typedef float v4f __attribute__((ext_vector_type(4)));

__device__ __forceinline__ void gl_lds16(const void* g, void* l) {
    __builtin_amdgcn_global_load_lds((const __attribute__((address_space(1))) void*)g,
                                     (__attribute__((address_space(3))) void*)l, 16, 0, 0);
}
__device__ __forceinline__ unsigned short f2bf(float f) {   // RNE, finite inputs
    unsigned int u = __float_as_uint(f);
    return (unsigned short)((u + 0x7FFFu + ((u >> 16) & 1u)) >> 16);
}
// monotone float<->uint encoding for atomicMax on floats of any sign
__device__ __forceinline__ unsigned fenc(float f) {
    unsigned u = __float_as_uint(f);
    return (u & 0x80000000u) ? ~u : (u | 0x80000000u);
}
__device__ __forceinline__ float fdec(unsigned m) {
    unsigned u = (m & 0x80000000u) ? (m & 0x7fffffffu) : ~m;
    return __uint_as_float(u);
}

// ---------------- P0: z BCHW fp32 -> zb16[n][c] bf16 (transpose+cast) ----------------
__global__ void k_prep_z(const float* __restrict__ z, unsigned short* __restrict__ zb16) {
    __shared__ float ts[64][65];
    const int hw0 = blockIdx.x * 64, c0 = blockIdx.y * 64, b = blockIdx.z;
    const int tid = threadIdx.x;
#pragma unroll
    for (int p = 0; p < 4; ++p) {
        int u = p * 256 + tid;
        int ci = u >> 4, j4 = (u & 15) << 2;
        float4 v = *(const float4*)(z + (size_t)b * 262144 + (size_t)(c0 + ci) * 1024 + hw0 + j4);
        ts[ci][j4 + 0] = v.x; ts[ci][j4 + 1] = v.y; ts[ci][j4 + 2] = v.z; ts[ci][j4 + 3] = v.w;
    }
    __syncthreads();
#pragma unroll
    for (int p = 0; p < 4; ++p) {
        int u = p * 256 + tid;
        int hj = u >> 4, i4 = (u & 15) << 2;
        ushort4 o = make_ushort4(f2bf(ts[i4 + 0][hj]), f2bf(ts[i4 + 1][hj]),
                                 f2bf(ts[i4 + 2][hj]), f2bf(ts[i4 + 3][hj]));
        *(ushort4*)(zb16 + (size_t)(b * 1024 + hw0 + hj) * 256 + c0 + i4) = o;
    }
}

// ---------------- P1: emb fp32 -> ebf[k][c] bf16, fused with enorm + lossAcc=0 -------
__global__ void k_prep_e(const float* __restrict__ emb, unsigned short* __restrict__ ebf,
                         float* __restrict__ enorm, float* __restrict__ lossAcc) {
    const int w = threadIdx.x >> 6, lane = threadIdx.x & 63;
    const int k = blockIdx.x * 4 + w;
    const int i = k * CC + lane * 4;
    float4 v = *(const float4*)(emb + i);
    *(ushort4*)(ebf + i) = make_ushort4(f2bf(v.x), f2bf(v.y), f2bf(v.z), f2bf(v.w));
    float s = v.x * v.x + v.y * v.y + v.z * v.z + v.w * v.w;
    for (int off = 32; off > 0; off >>= 1) s += __shfl_down(s, off);
    if (lane == 0) enorm[k] = s;
    if (blockIdx.x == 0 && threadIdx.x == 0) lossAcc[0] = 0.0f;
}

// ---------------- Phase 1: single-sweep MFMA candidate generation -------------------
// ROUND-6 structure (verified 149.6us) + depth-3 A-prefetch ring (the one change).
// 256 blocks x 512 thr (8 waves, 2/SIMD, 256-reg budget). Block = 64 n; B z-tile
// staged ONCE in LDS (32 KB, shared by all 8 waves -> A reuse 4 MFMA/fragment, block
// reads ebf exactly once = 4 MB; round-7 lesson: protect this). Wave w sweeps chunks
// ci = s*8 + w (64 k each), strided so blocks share a sliding L2 window.
// A ring: 4 buffers aR[4], slot = cc&3 (8-step unrolled loop, 8%4==0 -> static
// indices every s). At step cc we issue the load for step cc+3 (~234 cy of MFMA
// ahead) -- covers L2 latency; per-register counted vmcnt keeps 3 loads in flight,
// and the s-epilogue VALU work overlaps the 3 cross-boundary prefetches.
// B ping-pong depth-1 from LDS (latency ~120cy, mostly covered by 78cy MFMA).
// Reg budget: A-ring 64 + B 32 + acc 64 (AGPR) + misc ~30 < 256. Spill tripwire:
// WRITE_SIZE (clean ~0.6 MB).
// Candidate semantics unchanged (verified rounds 4-7): progressive threshold
// max(shared runmax, own chunk max) - MARGIN (superset-safe under staleness),
// (k,dot) -> LDS lists, exact final filter vs TRUE block-global max, overflow ->
// full-scan fallback.
// mfma_f32_16x16x32_bf16: A[m=lane&15][c=(lane>>4)*8+j]; B[c][n=lane&15];
// D: col(n)=lane&15, row(k)=(lane>>4)*4+reg.
__global__ __launch_bounds__(512, 2)
void k_cand(const unsigned short* __restrict__ zb16, const unsigned short* __restrict__ ebf,
            int* __restrict__ candCnt, int* __restrict__ candI) {
    __shared__ short    Bs[8][4][512];      // 32 KB  [cchunk][ntile][lane*8]
    __shared__ unsigned runmaxU[64];        // ordered-uint running max per n
    __shared__ int      cnt[64];
    __shared__ int      lstK[64][LCAP];     // 24 KB
    __shared__ float    lstD[64][LCAP];     // 24 KB

    const int tid  = threadIdx.x;
    const int lane = tid & 63;
    const int w    = tid >> 6;              // 0..7
    const int nb   = blockIdx.x << 6;
    const int m16  = lane & 15, q = lane >> 4;

    if (tid < 64) { runmaxU[tid] = 0x007FFFFFu; /* fenc(-inf) */ cnt[tid] = 0; }

    // stage B-tile once: 32 (cc,nt) fragments x 64 lanes x 16B; 4 per wave
#pragma unroll
    for (int p = 0; p < 4; ++p) {
        const int g8 = p * 8 + w;          // 0..31, wave-uniform
        const int cc = g8 >> 2, nt = g8 & 3;
        const unsigned short* g = zb16 + (size_t)(nb + nt * 16 + m16) * 256 + cc * 32 + q * 8;
        gl_lds16(g, &Bs[cc][nt][lane * 8]);
    }

    auto loadA = [&](v8s (&a)[4], int kbr, int cc) {
#pragma unroll
        for (int kt = 0; kt < 4; ++kt)
            a[kt] = *(const v8s*)(ebf + (size_t)(kbr + (kt << 4) + m16) * 256 + (cc << 5) + q * 8);
    };
    auto loadB = [&](v8s (&b)[4], int cc) {
#pragma unroll
        for (int nt = 0; nt < 4; ++nt) b[nt] = *(const v8s*)&Bs[cc][nt][lane * 8];
    };

    v8s aR[4][4];            // A ring (static indices only -- cc fully unrolled)
    v8s bP[4], bN[4];

    // prologue: seed ring with (s=0, cc=0,1,2); registers only, safe pre-barrier
    const int kb0 = w << 6;                // s=0 -> ci=w
    loadA(aR[0], kb0, 0);
    loadA(aR[1], kb0, 1);
    loadA(aR[2], kb0, 2);
    __syncthreads();       // Bs staged + runmaxU/cnt init visible (drains vmcnt once)
    loadB(bP, 0);

#pragma unroll 1
    for (int s = 0; s < 16; ++s) {
        const int kb  = ((s << 3) + w) << 6;           // this wave's chunk (64 k)
        const int kbn = (s < 15) ? kb + 512 : kb;      // next s's chunk (ci+8)
        v4f acc[16];
#pragma unroll
        for (int i = 0; i < 16; ++i) acc[i] = (v4f){0.f, 0.f, 0.f, 0.f};

#pragma unroll
        for (int cc = 0; cc < 8; ++cc) {
            // B ping-pong: prefetch next cc (B(cc) is the same LDS data every s,
            // so (cc+1)&7 at cc=7 pre-loads next-s cc=0).
            if ((cc & 1) == 0) loadB(bN, (cc + 1) & 7);
            else               loadB(bP, (cc + 1) & 7);
            // A ring: issue load for step cc+3 into slot (cc+3)&3
            {
                const int tcc = cc + 3;
                if (tcc < 8) loadA(aR[tcc & 3], kb,  tcc);
                else         loadA(aR[tcc & 3], kbn, tcc - 8);
            }
            // MFMA with slot cc&3 (loaded 3 steps ago) and the cc-parity B buffer
#pragma unroll
            for (int kt = 0; kt < 4; ++kt)
#pragma unroll
                for (int nt = 0; nt < 4; ++nt)
                    acc[kt * 4 + nt] = __builtin_amdgcn_mfma_f32_16x16x32_bf16(
                        aR[cc & 3][kt], ((cc & 1) ? bN[nt] : bP[nt]),
                        acc[kt * 4 + nt], 0, 0, 0);
        }

        // chunk epilogue: own-chunk max per n-column, merge into shared runmax, push.
        // (3 A-loads for next s are in flight across this VALU section.)
        float mx[4];
#pragma unroll
        for (int nt = 0; nt < 4; ++nt) {
            float m = acc[0 * 4 + nt][0];
#pragma unroll
            for (int kt = 0; kt < 4; ++kt)
#pragma unroll
                for (int r = 0; r < 4; ++r) m = fmaxf(m, acc[kt * 4 + nt][r]);
            m = fmaxf(m, __shfl_xor(m, 16));
            m = fmaxf(m, __shfl_xor(m, 32));
            mx[nt] = m;                     // all lanes: chunk max of column n=nt*16+m16
            if (lane < 16) atomicMax(&runmaxU[nt * 16 + lane], fenc(m));
        }
#pragma unroll
        for (int nt = 0; nt < 4; ++nt) {
            const int nl = nt * 16 + m16;
            const float thr = fmaxf(fdec(runmaxU[nl]), mx[nt]) - MARGIN;
#pragma unroll
            for (int kt = 0; kt < 4; ++kt)
#pragma unroll
                for (int r = 0; r < 4; ++r) {
                    if (acc[kt * 4 + nt][r] >= thr) {
                        int k = kb + (kt << 4) + q * 4 + r;
                        int pos = atomicAdd(&cnt[nl], 1);
                        if (pos < LCAP) { lstK[nl][pos] = k; lstD[nl][pos] = acc[kt * 4 + nt][r]; }
                    }
                }
        }
        if (s == 3 || s == 9) __syncthreads();   // bound cross-wave staleness
    }

    __syncthreads();   // all pushes + atomicMax done; runmaxU now TRUE global max per n
    if (tid < 64) {
        const int n = nb + tid;
        const int c = cnt[tid];
        if (c > LCAP) {
            candCnt[n] = KK;               // overflow -> exact full-scan fallback
        } else {
            const float thr = fdec(runmaxU[tid]) - MARGIN;
            int kept = 0;
            for (int i = 0; i < c; ++i) {
                if (lstD[tid][i] >= thr) {
                    if (kept < CAND_CAP) candI[(size_t)n * CAND_CAP + kept] = lstK[tid][i];
                    ++kept;
                }
            }
            candCnt[n] = (kept > CAND_CAP) ? KK : kept;
        }
    }
}

// ---------------- Phase 2 (fused): transpose-stage + rescore + gather + loss ---------
// 512 blocks x 256 thr (4 waves). Block = 32 consecutive hw (b = bid>>5, hw0 =
// (bid&31)*32). LDS 33.4 KB -> 4 blocks/CU -> 4 waves/SIMD (round-7 k_final at 256
// blocks/67KB was 2/SIMD and latency-bound in the serial rescore: 16 rows/wave).
// Pad 261: staging scatter-write 2-way (free), rescore b128 row-read structural-min.
// Rescore: wave per n (8 per wave), lane l holds zl[j][4l..4l+3] -- same values and
// dot chain as the verified round-7 kernel. zn butterfly shifts all d of an n
// equally -> argmin/tie-break invariant. d = (zn + enorm[k]) - (p+p); ties -> min k.
__global__ __launch_bounds__(256)
void k_final(const float* __restrict__ z, const float* __restrict__ emb,
             const float* __restrict__ enorm, const int* __restrict__ candCnt,
             const int* __restrict__ candI, float* __restrict__ out,
             float* __restrict__ idxf, float* __restrict__ lossAcc) {
    __shared__ float zl[32][261];     // [hw][c], 33.4 KB
    __shared__ int   kis[32];
    __shared__ float red[256];
    const int bid = blockIdx.x;
    const int b = bid >> 5, hw0 = (bid & 31) << 5;
    const int tid = threadIdx.x;
    const int lane = tid & 63, w = tid >> 6;

    // stage: read float4 along hw (coalesced 128B/row-group), transpose into zl[hw][c]
#pragma unroll
    for (int p = 0; p < 8; ++p) {
        const int u = p * 256 + tid;
        const int c = u >> 3, j4 = (u & 7) << 2;
        float4 v = *(const float4*)(z + (size_t)b * 262144 + (size_t)c * 1024 + hw0 + j4);
        zl[j4 + 0][c] = v.x; zl[j4 + 1][c] = v.y; zl[j4 + 2][c] = v.z; zl[j4 + 3][c] = v.w;
    }
    __syncthreads();

    // rescore: wave per n, 8 n per wave
#pragma unroll 1
    for (int rr = 0; rr < 8; ++rr) {
        const int j = w * 8 + rr;
        const int n = b * 1024 + hw0 + j;
        const float4 zv = *(const float4*)&zl[j][lane * 4];
        float zn = zv.x * zv.x;
        zn = fmaf(zv.y, zv.y, zn); zn = fmaf(zv.z, zv.z, zn); zn = fmaf(zv.w, zv.w, zn);
#pragma unroll
        for (int off = 1; off < 64; off <<= 1) zn += __shfl_xor(zn, off);
        const int cnt = candCnt[n];
        float bd = __builtin_inff();
        int   bk = 0x7fffffff;
        if (cnt <= CAND_CAP) {
#pragma unroll 1
            for (int i = 0; i < cnt; ++i) {
                const int k = candI[(size_t)n * CAND_CAP + i];
                const float4 ev = *(const float4*)(emb + (size_t)k * CC + lane * 4);
                float p = zv.x * ev.x;
                p = fmaf(zv.y, ev.y, p);
                p = fmaf(zv.z, ev.z, p);
                p = fmaf(zv.w, ev.w, p);
#pragma unroll
                for (int off = 1; off < 64; off <<= 1) p += __shfl_xor(p, off);
                const float d = (zn + enorm[k]) - (p + p);
                if (d < bd || (d == bd && k < bk)) { bd = d; bk = k; }
            }
        } else {
            // overflow fallback: exact full scan, ascending k keeps min-k
#pragma unroll 1
            for (int k = 0; k < KK; ++k) {
                const float4 ev = *(const float4*)(emb + (size_t)k * CC + lane * 4);
                float p = zv.x * ev.x;
                p = fmaf(zv.y, ev.y, p);
                p = fmaf(zv.z, ev.z, p);
                p = fmaf(zv.w, ev.w, p);
#pragma unroll
                for (int off = 1; off < 64; off <<= 1) p += __shfl_xor(p, off);
                const float d = (zn + enorm[k]) - (p + p);
                if (d < bd) { bd = d; bk = k; }
            }
        }
        if (lane == 0) { idxf[n] = (float)bk; kis[j] = bk; }
    }
    __syncthreads();

    // gather z_q (BCHW, coalesced along hw) + loss partials from the LDS tile
    const int j  = tid & 31;          // hw within tile
    const int cg = tid >> 5;          // c-group of 32
    const int ki0 = kis[j];
    const float* ep = emb + (size_t)ki0 * CC;
    float ls = 0.0f;
#pragma unroll 4
    for (int c = cg * 32; c < cg * 32 + 32; ++c) {
        float e  = ep[c];
        float zv = zl[j][c];
        out[(size_t)b * 262144 + (size_t)c * 1024 + hw0 + j] = e;
        float df = e - zv;
        ls = fmaf(df, df, ls);
    }
    red[tid] = ls;
    __syncthreads();
    for (int s2 = 128; s2 > 0; s2 >>= 1) {
        if (tid < s2) red[tid] += red[tid + s2];
        __syncthreads();
    }
    if (tid == 0) atomicAdd(lossAcc, red[0]);
}

// ---------------- finalize loss ----------------
__global__ void k_loss(const float* __restrict__ lossAcc, float* __restrict__ outLoss) {
    if (threadIdx.x == 0) {
        float m = lossAcc[0] * (1.0f / 4194304.0f);
        outLoss[0] = m + 0.25f * m;
    }
}

extern "C" void kernel_launch(void* const* d_in, const int* in_sizes, int n_in,
                              void* d_out, int out_size, void* d_ws, size_t ws_size,
                              hipStream_t stream) {
    const float* z   = (const float*)d_in[0];
    const float* emb = (const float*)d_in[1];
    float* outf = (float*)d_out;
    float* wsf  = (float*)d_ws;

    float* lossAcc = wsf;
    float* enorm   = wsf + WS_ENORM;
    int*   candCnt = (int*)(wsf + WS_CCNT);
    int*   candI   = (int*)(wsf + WS_CIDX);

    // d_out z_q region doubles as scratch: bf16 zb16/ebf until k_cand completes,
    // then k_final overwrites it with z_q.
    unsigned short* zb16 = (unsigned short*)outf;                  // 8 MB
    unsigned short* ebf  = (unsigned short*)(outf + 2097152);      // 4 MB

    k_prep_e<<<2048, 256, 0, stream>>>(emb, ebf, enorm, lossAcc);
    k_prep_z<<<dim3(16, 4, 16), 256, 0, stream>>>(z, zb16);
    k_cand<<<256, 512, 0, stream>>>(zb16, ebf, candCnt, candI);
    k_final<<<512, 256, 0, stream>>>(z, emb, enorm, candCnt, candI,
                                     outf, outf + Z_OUT, lossAcc);
    k_loss<<<1, 64, 0, stream>>>(lossAcc, outf + Z_OUT + NPTS);
}